// Round 12
// baseline (162.404 us; speedup 1.0000x reference)
//
#include <hip/hip_runtime.h>

#define HIN 192
#define WOUT 384
#define NIN 32
#define NOUT 16
#define NSLOT 9
#define HP 194
#define HPLANE (HP * HP)                   // positions per plane (37636)
#define HQBATCH ((size_t)HPLANE * 18)      // uint4 elems per batch (18 quad-planes)
#define NSTG (18 * 3 * 66)                 // staged uint4 per block (3564)

typedef float v2f __attribute__((ext_vector_type(2)));

__device__ __forceinline__ unsigned short f2bf(float f) {
    union { float f; unsigned int u; } v; v.f = f;
    unsigned int r = v.u + 0x7fffu + ((v.u >> 16) & 1u);   // RNE
    return (unsigned short)(r >> 16);
}
__device__ __forceinline__ v2f up2(unsigned u) {
    v2f r;
    r.x = __uint_as_float(u << 16);
    r.y = __uint_as_float(u & 0xffff0000u);
    return r;
}

// ---- prep: Wt[c*256 + i*8 + j] = W[o][i][s],  m=c*8+j, s=m>>4, o=m&15 ----
__global__ __launch_bounds__(256) void kprep_w(const float* __restrict__ w, float* __restrict__ Wt) {
    int t = blockIdx.x * 256 + threadIdx.x;
    if (t >= NIN * NSLOT * NOUT) return;   // 4608
    int c = t >> 8, r = t & 255;
    int i = r >> 3, j = r & 7;
    int m = c * 8 + j;
    int s = m >> 4, o = m & 15;
    Wt[t] = w[(o * NIN + i) * NSLOT + s];
}

// ---- zero the 1-px halo border of every quad-plane ----
__global__ __launch_bounds__(256) void kzero(uint4* __restrict__ hq, int nb) {
    int t = blockIdx.x * 256 + threadIdx.x;
    if (t >= nb * 772) return;
    int b = t / 772, r = t % 772;
    int iy, ix;
    if (r < 194)      { iy = 0;           ix = r; }
    else if (r < 388) { iy = 193;         ix = r - 194; }
    else if (r < 580) { iy = r - 388 + 1; ix = 0; }
    else              { iy = r - 580 + 1; ix = 193; }
    uint4* p = hq + (size_t)b * HQBATCH + iy * HP + ix;
    uint4 z; z.x = 0; z.y = 0; z.z = 0; z.w = 0;
    #pragma unroll
    for (int c = 0; c < 18; ++c) p[(size_t)c * HPLANE] = z;
}

// ---- kA: channel mix at input resolution -> quad-plane bf16 pairs (pk_fma accum) ----
__global__ __launch_bounds__(256) void kA(const float* __restrict__ x,
                                          const float* __restrict__ Wt,
                                          uint4* __restrict__ hq, int n0) {
    const int b = blockIdx.y;
    const int n = n0 + b;
    const int px = blockIdx.x * 256 + threadIdx.x;   // 0..36863
    const int iy = px / HIN, ix = px % HIN;
    const float* xp = x + (size_t)n * NIN * HIN * HIN + px;
    float xv[NIN];
    #pragma unroll
    for (int i = 0; i < NIN; ++i) xv[i] = xp[(size_t)i * HIN * HIN];
    const int pos = (iy + 1) * HP + (ix + 1);
    uint4* hb = hq + (size_t)b * HQBATCH;
    #pragma unroll 1
    for (int c = 0; c < 18; ++c) {
        const float* wc = Wt + c * 256;              // uniform -> scalar loads
        v2f a2[4];
        #pragma unroll
        for (int j = 0; j < 4; ++j) { a2[j].x = 0.0f; a2[j].y = 0.0f; }
        #pragma unroll
        for (int i = 0; i < NIN; ++i) {
            const float xi = xv[i];
            v2f x2; x2.x = xi; x2.y = xi;
            #pragma unroll
            for (int j = 0; j < 4; ++j) {
                v2f w2;
                w2.x = wc[i * 8 + 2 * j];
                w2.y = wc[i * 8 + 2 * j + 1];
                a2[j] += w2 * x2;                    // fp-contract -> pk_fma
            }
        }
        uint4 v;
        v.x = (unsigned)f2bf(a2[0].x) | ((unsigned)f2bf(a2[0].y) << 16);
        v.y = (unsigned)f2bf(a2[1].x) | ((unsigned)f2bf(a2[1].y) << 16);
        v.z = (unsigned)f2bf(a2[2].x) | ((unsigned)f2bf(a2[2].y) << 16);
        v.w = (unsigned)f2bf(a2[3].x) | ((unsigned)f2bf(a2[3].y) << 16);
        hb[(size_t)c * HPLANE + pos] = v;
    }
}

// ---- kB body: taps from LDS; one wave = (parity, half); one thread = one site, 8 ch ----
template<int PY, int PX, int HF>
__device__ __forceinline__ void kb_body(const uint4* __restrict__ ringp,
                                        const float* __restrict__ alpha,
                                        const float* __restrict__ bias_,
                                        float (&stage)[2][16][128],
                                        const float2 (&Cb)[NSLOT][25],
                                        int n, int Y, int X, int lane) {
    const int oy = 2 * Y + PY, ox = 2 * X + PX;
    const int aoff = (n * WOUT + oy) * WOUT + ox;
    const float a0 = alpha[aoff];
    const float a1 = alpha[(size_t)8 * WOUT * WOUT + aoff];
    const float rr = sqrtf(a0 * a0 + a1 * a1);
    const float inv = 1.0f / (rr + 1e-8f);
    float cc[3], ss[3];
    cc[0] = a0 * inv;                      ss[0] = a1 * inv;
    cc[1] = cc[0] * cc[0] - ss[0] * ss[0]; ss[1] = 2.0f * cc[0] * ss[0];
    cc[2] = cc[1] * cc[0] - ss[1] * ss[0]; ss[2] = ss[1] * cc[0] + cc[1] * ss[0];

    v2f acc2[4];
    #pragma unroll
    for (int j = 0; j < 4; ++j) { acc2[j].x = 0.0f; acc2[j].y = 0.0f; }

    #pragma unroll 1
    for (int ty = 0; ty < 3 - PY; ++ty) {           // ky = PY + 2*ty <= 4
        #pragma unroll 1
        for (int tx = 0; tx < 3 - PX; ++tx) {       // kx = PX + 2*tx <= 4
            const int bi = (PY + 2 * ty) * 5 + (PX + 2 * tx);
            // base LDS record for this tap; slots at compile-time offsets s*396 uint4
            const uint4* rp = ringp + HF * 198 + (2 - ty) * 66 + (lane + 2 - tx);
            #pragma unroll
            for (int s = 0; s < NSLOT; ++s) {
                const float2 C = Cb[s][bi];
                float eb;
                if      (s < 3) eb = C.x;
                else if (s < 5) eb = C.x * cc[0] + C.y * ss[0];
                else if (s < 7) eb = C.x * cc[1] + C.y * ss[1];
                else            eb = C.x * cc[2] + C.y * ss[2];
                const uint4 v = rp[s * 396];        // ds_read_b128, offset immediate
                v2f e2; e2.x = eb; e2.y = eb;
                acc2[0] += e2 * up2(v.x);
                acc2[1] += e2 * up2(v.y);
                acc2[2] += e2 * up2(v.z);
                acc2[3] += e2 * up2(v.w);
            }
        }
    }

    #pragma unroll
    for (int j = 0; j < 4; ++j) {
        stage[PY][HF * 8 + 2 * j + 0][2 * lane + PX] = rr * acc2[j].x + bias_[HF * 8 + 2 * j + 0];
        stage[PY][HF * 8 + 2 * j + 1][2 * lane + PX] = rr * acc2[j].y + bias_[HF * 8 + 2 * j + 1];
    }
}

__global__ __launch_bounds__(512, 4) void kB(const uint4* __restrict__ hq,
                                             const float* __restrict__ alpha,
                                             const float* __restrict__ bias,
                                             float* __restrict__ out, int n0, int nb) {
    __shared__ float2 Cb[NSLOT][25];
    __shared__ __align__(16) uint4 ring[NSTG];      // [plane][row][pos] = [18][3][66]
    __shared__ float stage[2][16][128];
    {
        const int q = threadIdx.x;
        if (q < NSLOT * 25) {
            int s = q / 25, p = q % 25;
            int ky = p / 5, kx = p % 5;
            float ys = (float)(ky - 2), xs = (float)(kx - 2);
            float r = sqrtf(xs * xs + ys * ys);
            float th = atan2f(ys, xs);
            float cr, ci;
            if (s < 3) {
                float d = r - (float)s;
                cr = expf(-d * d * (1.0f / 0.72f));
                ci = 0.0f;
            } else {
                int k = (s - 3) / 2 + 1;
                float r0 = ((s - 3) & 1) ? 2.0f : 1.0f;
                float d = r - r0;
                float rg = expf(-d * d * (1.0f / 0.72f));
                float a = (float)k * th;
                cr = rg * cosf(a);
                ci = rg * sinf(a);
            }
            Cb[s][p] = make_float2(cr, ci);
        }
    }

    // ---- bijective XCD swizzle, Y-fastest ----
    const int tot = gridDim.x;
    const int cpx = tot >> 3;
    const int swz = ((int)blockIdx.x & 7) * cpx + ((int)blockIdx.x >> 3);
    const int Y = swz % 192;
    const int rest = swz / 192;
    const int b = rest % nb;
    const int bx = rest / nb;

    const int n = n0 + b;
    const int lane = threadIdx.x & 63;
    const int wv = threadIdx.x >> 6;        // 0..7 = (half, parity)
    const int X0 = bx * 64;
    const int X = X0 + lane;
    const uint4* hb = hq + (size_t)b * HQBATCH;

    // ---- one-shot cooperative stage: 18 planes x 3 rows x 66 positions ----
    for (int it = threadIdx.x; it < NSTG; it += 512) {
        const int pl = it / 198;
        const int rm = it - pl * 198;
        const int row = rm / 66;
        const int pos = rm - row * 66;
        ring[it] = hb[(size_t)pl * HPLANE + (size_t)(Y + row) * HP + X0 + pos];
    }
    __syncthreads();

    switch (wv) {
        case 0: kb_body<0, 0, 0>(ring, alpha, bias, stage, Cb, n, Y, X, lane); break;
        case 1: kb_body<0, 1, 0>(ring, alpha, bias, stage, Cb, n, Y, X, lane); break;
        case 2: kb_body<1, 0, 0>(ring, alpha, bias, stage, Cb, n, Y, X, lane); break;
        case 3: kb_body<1, 1, 0>(ring, alpha, bias, stage, Cb, n, Y, X, lane); break;
        case 4: kb_body<0, 0, 1>(ring, alpha, bias, stage, Cb, n, Y, X, lane); break;
        case 5: kb_body<0, 1, 1>(ring, alpha, bias, stage, Cb, n, Y, X, lane); break;
        case 6: kb_body<1, 0, 1>(ring, alpha, bias, stage, Cb, n, Y, X, lane); break;
        default: kb_body<1, 1, 1>(ring, alpha, bias, stage, Cb, n, Y, X, lane); break;
    }

    __syncthreads();

    // cooperative coalesced store: 2 oy-rows x 16 channels x 128 px (4096 floats)
    #pragma unroll
    for (int q = 0; q < 8; ++q) {
        const int f = q * 512 + threadIdx.x;
        const int row = f >> 7, col = f & 127;
        const int py = row >> 4, o = row & 15;
        out[(((size_t)n * NOUT + o) * WOUT + (2 * Y + py)) * WOUT + 2 * X0 + col]
            = stage[py][o][col];
    }
}

// ---- fallback: proven round-1 monolithic kernel ----
__global__ __launch_bounds__(256) void steered_convT(
    const float* __restrict__ x, const float* __restrict__ alpha,
    const float* __restrict__ weights, const float* __restrict__ bias,
    float* __restrict__ out) {
    __shared__ float sb[15 * 25];
    for (int q = threadIdx.x; q < 375; q += 256) {
        int s = q / 25, p = q % 25;
        int ky = p / 5, kx = p % 5;
        float ys = (float)(ky - 2), xs = (float)(kx - 2);
        float r = sqrtf(xs * xs + ys * ys);
        float th = atan2f(ys, xs);
        float val;
        if (s < 3) { float d = r - (float)s; val = expf(-d * d * (1.0f / 0.72f)); }
        else {
            int k = (s - 3) / 4 + 1; int rem = (s - 3) & 3;
            float r0 = (rem & 1) ? 2.0f : 1.0f; float d = r - r0;
            float ring = expf(-d * d * (1.0f / 0.72f));
            float ang = (float)k * th;
            val = ring * ((rem < 2) ? cosf(ang) : sinf(ang));
        }
        sb[q] = val;
    }
    __syncthreads();
    int idx = blockIdx.x * 256 + threadIdx.x;
    int ox = idx % WOUT; int tt = idx / WOUT; int oy = tt % WOUT; int n = tt / WOUT;
    const int plane = WOUT * WOUT;
    int aoff = (n * WOUT + oy) * WOUT + ox;
    float a0 = alpha[aoff], a1 = alpha[8 * plane + aoff];
    float rho = sqrtf(a0 * a0 + a1 * a1);
    float inv = 1.0f / (rho + 1e-8f);
    float c1 = a0 * inv, s1 = a1 * inv;
    float c2 = c1 * c1 - s1 * s1, s2 = 2.0f * s1 * c1;
    float c3 = c2 * c1 - s2 * s1, s3 = s2 * c1 + c2 * s1;
    int py = oy & 1, px = ox & 1;
    int iy0 = (oy >> 1) + 1, ix0 = (ox >> 1) + 1;
    float eb[9][9]; int off[9];
    #pragma unroll
    for (int t = 0; t < 9; ++t) {
        int ty = t / 3, tx = t % 3;
        int ky = py + 2 * ty, kx = px + 2 * tx;
        int iy = iy0 - ty, ix = ix0 - tx;
        bool v = (ky < 5) && (kx < 5) && (iy >= 0) && (iy < HIN) && (ix >= 0) && (ix < HIN);
        float m = v ? 1.0f : 0.0f;
        int ciy = min(max(iy, 0), HIN - 1), cix = min(max(ix, 0), HIN - 1);
        off[t] = ciy * HIN + cix;
        int bi_ = min(ky, 4) * 5 + min(kx, 4);
        eb[0][t] = sb[0 * 25 + bi_] * m;
        eb[1][t] = sb[1 * 25 + bi_] * m;
        eb[2][t] = sb[2 * 25 + bi_] * m;
        eb[3][t] = (sb[3 * 25 + bi_] * c1 + sb[5 * 25 + bi_] * s1) * m;
        eb[4][t] = (sb[4 * 25 + bi_] * c1 + sb[6 * 25 + bi_] * s1) * m;
        eb[5][t] = (sb[7 * 25 + bi_] * c2 + sb[9 * 25 + bi_] * s2) * m;
        eb[6][t] = (sb[8 * 25 + bi_] * c2 + sb[10 * 25 + bi_] * s2) * m;
        eb[7][t] = (sb[11 * 25 + bi_] * c3 + sb[13 * 25 + bi_] * s3) * m;
        eb[8][t] = (sb[12 * 25 + bi_] * c3 + sb[14 * 25 + bi_] * s3) * m;
    }
    float acc[NOUT];
    #pragma unroll
    for (int o = 0; o < NOUT; ++o) acc[o] = 0.0f;
    const float* xn = x + (size_t)n * NIN * HIN * HIN;
    for (int i = 0; i < NIN; ++i) {
        const float* xp = xn + (size_t)i * HIN * HIN;
        float tap[9];
        #pragma unroll
        for (int t = 0; t < 9; ++t) tap[t] = xp[off[t]];
        float G[9];
        #pragma unroll
        for (int b = 0; b < 9; ++b) {
            float s = 0.0f;
            #pragma unroll
            for (int t = 0; t < 9; ++t) s += eb[b][t] * tap[t];
            G[b] = s;
        }
        const float* wp = weights + i * 9;
        #pragma unroll
        for (int o = 0; o < NOUT; ++o) {
            float s = acc[o];
            #pragma unroll
            for (int b = 0; b < 9; ++b) s += wp[o * NIN * 9 + b] * G[b];
            acc[o] = s;
        }
    }
    #pragma unroll
    for (int o = 0; o < NOUT; ++o)
        out[((size_t)(n * NOUT + o) * WOUT + oy) * WOUT + ox] = rho * acc[o] + bias[o];
}

extern "C" void kernel_launch(void* const* d_in, const int* in_sizes, int n_in,
                              void* d_out, int out_size, void* d_ws, size_t ws_size,
                              hipStream_t stream) {
    const float* x       = (const float*)d_in[0];
    const float* alpha   = (const float*)d_in[1];
    const float* weights = (const float*)d_in[2];
    const float* bias    = (const float*)d_in[3];
    float* out = (float*)d_out;

    const size_t hoff = 32768;
    const size_t perb = HQBATCH * 16;        // bytes per batch of h
    int cb = 0;
    if (ws_size > hoff) cb = (int)((ws_size - hoff) / perb);
    if (cb > 8) cb = 8;

    if (cb < 1) {
        const int pixels = 8 * WOUT * WOUT;
        steered_convT<<<dim3(pixels / 256), 256, 0, stream>>>(x, alpha, weights, bias, out);
        return;
    }

    float* Wt = (float*)d_ws;
    uint4* hq = (uint4*)((char*)d_ws + hoff);

    kprep_w<<<dim3(18), 256, 0, stream>>>(weights, Wt);

    for (int n0 = 0; n0 < 8; n0 += cb) {
        int nb = 8 - n0; if (nb > cb) nb = cb;
        kzero<<<dim3((nb * 772 + 255) / 256), 256, 0, stream>>>(hq, nb);
        kA<<<dim3(144, nb), 256, 0, stream>>>(x, Wt, hq, n0);
        kB<<<dim3(576 * nb), 512, 0, stream>>>(hq, alpha, bias, out, n0, nb);
    }
}

// Round 13
// 150.092 us; speedup vs baseline: 1.0820x; 1.0820x over previous
//
#include <hip/hip_runtime.h>

#define HIN 192
#define WOUT 384
#define NIN 32
#define NOUT 16
#define NSLOT 9
#define HP 194
#define HPLANE (HP * HP)                   // positions per plane (37636)
#define HQBATCH ((size_t)HPLANE * 18)      // uint4 elems per batch (18 quad-planes)

typedef float v2f __attribute__((ext_vector_type(2)));

__device__ __forceinline__ unsigned short f2bf(float f) {
    union { float f; unsigned int u; } v; v.f = f;
    unsigned int r = v.u + 0x7fffu + ((v.u >> 16) & 1u);   // RNE
    return (unsigned short)(r >> 16);
}
// lo: exact bf16 (shift). hi: RAW dword as f32 — bf16 in bits 31..16 plus 16 junk
// mantissa-tail bits (relative perturbation <= 2^-7, sign-random in the sum).
// Saves the v_and per dword; error budget ~0.05 absolute vs 0.44 threshold.
__device__ __forceinline__ v2f up2(unsigned u) {
    v2f r;
    r.x = __uint_as_float(u << 16);
    r.y = __uint_as_float(u);
    return r;
}

// ---- prep: Wt[c*256 + i*8 + j] = W[o][i][s],  m=c*8+j, s=m>>4, o=m&15 ----
__global__ __launch_bounds__(256) void kprep_w(const float* __restrict__ w, float* __restrict__ Wt) {
    int t = blockIdx.x * 256 + threadIdx.x;
    if (t >= NIN * NSLOT * NOUT) return;   // 4608
    int c = t >> 8, r = t & 255;
    int i = r >> 3, j = r & 7;
    int m = c * 8 + j;
    int s = m >> 4, o = m & 15;
    Wt[t] = w[(o * NIN + i) * NSLOT + s];
}

// ---- zero the 1-px halo border of every quad-plane ----
__global__ __launch_bounds__(256) void kzero(uint4* __restrict__ hq, int nb) {
    int t = blockIdx.x * 256 + threadIdx.x;
    if (t >= nb * 772) return;
    int b = t / 772, r = t % 772;
    int iy, ix;
    if (r < 194)      { iy = 0;           ix = r; }
    else if (r < 388) { iy = 193;         ix = r - 194; }
    else if (r < 580) { iy = r - 388 + 1; ix = 0; }
    else              { iy = r - 580 + 1; ix = 193; }
    uint4* p = hq + (size_t)b * HQBATCH + iy * HP + ix;
    uint4 z; z.x = 0; z.y = 0; z.z = 0; z.w = 0;
    #pragma unroll
    for (int c = 0; c < 18; ++c) p[(size_t)c * HPLANE] = z;
}

// ---- kA: channel mix at input resolution -> quad-plane bf16 pairs ----
__global__ __launch_bounds__(256) void kA(const float* __restrict__ x,
                                          const float* __restrict__ Wt,
                                          uint4* __restrict__ hq, int n0) {
    const int b = blockIdx.y;
    const int n = n0 + b;
    const int px = blockIdx.x * 256 + threadIdx.x;   // 0..36863
    const int iy = px / HIN, ix = px % HIN;
    const float* xp = x + (size_t)n * NIN * HIN * HIN + px;
    float xv[NIN];
    #pragma unroll
    for (int i = 0; i < NIN; ++i) xv[i] = xp[(size_t)i * HIN * HIN];
    const int pos = (iy + 1) * HP + (ix + 1);
    uint4* hb = hq + (size_t)b * HQBATCH;
    #pragma unroll 1
    for (int c = 0; c < 18; ++c) {
        const float* wc = Wt + c * 256;              // uniform -> scalar loads
        float a[8];
        #pragma unroll
        for (int j = 0; j < 8; ++j) a[j] = 0.0f;
        #pragma unroll
        for (int i = 0; i < NIN; ++i) {
            const float xi = xv[i];
            #pragma unroll
            for (int j = 0; j < 8; ++j) a[j] = fmaf(wc[i * 8 + j], xi, a[j]);
        }
        uint4 v;
        v.x = (unsigned)f2bf(a[0]) | ((unsigned)f2bf(a[1]) << 16);
        v.y = (unsigned)f2bf(a[2]) | ((unsigned)f2bf(a[3]) << 16);
        v.z = (unsigned)f2bf(a[4]) | ((unsigned)f2bf(a[5]) << 16);
        v.w = (unsigned)f2bf(a[6]) | ((unsigned)f2bf(a[7]) << 16);
        hb[(size_t)c * HPLANE + pos] = v;
    }
}

// ---- kB body: one wave = (parity, channel-half); one thread = one site, 8 channels ----
template<int PY, int PX, int HF>
__device__ __forceinline__ void kb_body(const uint4* __restrict__ hb,
                                        const float* __restrict__ alpha,
                                        const float* __restrict__ bias_,
                                        float (&stage)[2][16][128],
                                        const float2 (&Cb)[NSLOT][25],
                                        int n, int Y, int X, int lane) {
    const int oy = 2 * Y + PY, ox = 2 * X + PX;
    const int aoff = (n * WOUT + oy) * WOUT + ox;
    const float a0 = alpha[aoff];
    const float a1 = alpha[(size_t)8 * WOUT * WOUT + aoff];
    const float rr = sqrtf(a0 * a0 + a1 * a1);
    const float inv = 1.0f / (rr + 1e-8f);
    float cc[3], ss[3];
    cc[0] = a0 * inv;                      ss[0] = a1 * inv;
    cc[1] = cc[0] * cc[0] - ss[0] * ss[0]; ss[1] = 2.0f * cc[0] * ss[0];
    cc[2] = cc[1] * cc[0] - ss[1] * ss[0]; ss[2] = ss[1] * cc[0] + cc[1] * ss[0];

    v2f acc2[4];
    #pragma unroll
    for (int j = 0; j < 4; ++j) { acc2[j].x = 0.0f; acc2[j].y = 0.0f; }

    #pragma unroll 1
    for (int ty = 0; ty < 3 - PY; ++ty) {           // ky = PY + 2*ty <= 4
        const int piy = Y + 2 - ty;
        #pragma unroll 1
        for (int tx = 0; tx < 3 - PX; ++tx) {       // kx = PX + 2*tx <= 4
            const int pix = X + 2 - tx;
            const int bi = (PY + 2 * ty) * 5 + (PX + 2 * tx);
            const unsigned pos = (unsigned)(piy * HP + pix);
            #pragma unroll
            for (int s = 0; s < NSLOT; ++s) {
                const float2 C = Cb[s][bi];
                float eb;
                if      (s < 3) eb = C.x;
                else if (s < 5) eb = C.x * cc[0] + C.y * ss[0];
                else if (s < 7) eb = C.x * cc[1] + C.y * ss[1];
                else            eb = C.x * cc[2] + C.y * ss[2];
                const uint4 v = hb[(size_t)(2 * s + HF) * HPLANE + pos];
                v2f e2; e2.x = eb; e2.y = eb;
                acc2[0] += e2 * up2(v.x);            // fp-contract -> v_pk_fma_f32
                acc2[1] += e2 * up2(v.y);
                acc2[2] += e2 * up2(v.z);
                acc2[3] += e2 * up2(v.w);
            }
        }
    }

    #pragma unroll
    for (int j = 0; j < 4; ++j) {
        stage[PY][HF * 8 + 2 * j + 0][2 * lane + PX] = rr * acc2[j].x + bias_[HF * 8 + 2 * j + 0];
        stage[PY][HF * 8 + 2 * j + 1][2 * lane + PX] = rr * acc2[j].y + bias_[HF * 8 + 2 * j + 1];
    }
}

__global__ __launch_bounds__(512, 4) void kB(const uint4* __restrict__ hq,
                                             const float* __restrict__ alpha,
                                             const float* __restrict__ bias,
                                             float* __restrict__ out, int n0, int nb) {
    __shared__ float2 Cb[NSLOT][25];
    __shared__ float stage[2][16][128];
    {
        const int q = threadIdx.x;
        if (q < NSLOT * 25) {
            int s = q / 25, p = q % 25;
            int ky = p / 5, kx = p % 5;
            float ys = (float)(ky - 2), xs = (float)(kx - 2);
            float r = sqrtf(xs * xs + ys * ys);
            float th = atan2f(ys, xs);
            float cr, ci;
            if (s < 3) {
                float d = r - (float)s;
                cr = expf(-d * d * (1.0f / 0.72f));
                ci = 0.0f;
            } else {
                int k = (s - 3) / 2 + 1;
                float r0 = ((s - 3) & 1) ? 2.0f : 1.0f;
                float d = r - r0;
                float ring = expf(-d * d * (1.0f / 0.72f));
                float a = (float)k * th;
                cr = ring * cosf(a);
                ci = ring * sinf(a);
            }
            Cb[s][p] = make_float2(cr, ci);
        }
    }
    __syncthreads();

    // ---- bijective XCD swizzle, Y-fastest: consecutive Y rows land on one XCD ----
    // total = 576*nb, always divisible by 8.
    const int tot = gridDim.x;
    const int cpx = tot >> 3;
    const int swz = ((int)blockIdx.x & 7) * cpx + ((int)blockIdx.x >> 3);
    const int Y = swz % 192;
    const int rest = swz / 192;
    const int b = rest % nb;
    const int bx = rest / nb;

    const int n = n0 + b;
    const int lane = threadIdx.x & 63;
    const int wv = threadIdx.x >> 6;        // 0..7 = (half, parity)
    const int X0 = bx * 64;
    const int X = X0 + lane;
    const uint4* hb = hq + (size_t)b * HQBATCH;

    switch (wv) {
        case 0: kb_body<0, 0, 0>(hb, alpha, bias, stage, Cb, n, Y, X, lane); break;
        case 1: kb_body<0, 1, 0>(hb, alpha, bias, stage, Cb, n, Y, X, lane); break;
        case 2: kb_body<1, 0, 0>(hb, alpha, bias, stage, Cb, n, Y, X, lane); break;
        case 3: kb_body<1, 1, 0>(hb, alpha, bias, stage, Cb, n, Y, X, lane); break;
        case 4: kb_body<0, 0, 1>(hb, alpha, bias, stage, Cb, n, Y, X, lane); break;
        case 5: kb_body<0, 1, 1>(hb, alpha, bias, stage, Cb, n, Y, X, lane); break;
        case 6: kb_body<1, 0, 1>(hb, alpha, bias, stage, Cb, n, Y, X, lane); break;
        default: kb_body<1, 1, 1>(hb, alpha, bias, stage, Cb, n, Y, X, lane); break;
    }

    __syncthreads();

    // cooperative coalesced store: 2 oy-rows x 16 channels x 128 px (4096 floats)
    #pragma unroll
    for (int q = 0; q < 8; ++q) {
        const int f = q * 512 + threadIdx.x;
        const int row = f >> 7, col = f & 127;
        const int py = row >> 4, o = row & 15;
        out[(((size_t)n * NOUT + o) * WOUT + (2 * Y + py)) * WOUT + 2 * X0 + col]
            = stage[py][o][col];
    }
}

// ---- fallback: proven round-1 monolithic kernel ----
__global__ __launch_bounds__(256) void steered_convT(
    const float* __restrict__ x, const float* __restrict__ alpha,
    const float* __restrict__ weights, const float* __restrict__ bias,
    float* __restrict__ out) {
    __shared__ float sb[15 * 25];
    for (int q = threadIdx.x; q < 375; q += 256) {
        int s = q / 25, p = q % 25;
        int ky = p / 5, kx = p % 5;
        float ys = (float)(ky - 2), xs = (float)(kx - 2);
        float r = sqrtf(xs * xs + ys * ys);
        float th = atan2f(ys, xs);
        float val;
        if (s < 3) { float d = r - (float)s; val = expf(-d * d * (1.0f / 0.72f)); }
        else {
            int k = (s - 3) / 4 + 1; int rem = (s - 3) & 3;
            float r0 = (rem & 1) ? 2.0f : 1.0f; float d = r - r0;
            float ring = expf(-d * d * (1.0f / 0.72f));
            float ang = (float)k * th;
            val = ring * ((rem < 2) ? cosf(ang) : sinf(ang));
        }
        sb[q] = val;
    }
    __syncthreads();
    int idx = blockIdx.x * 256 + threadIdx.x;
    int ox = idx % WOUT; int tt = idx / WOUT; int oy = tt % WOUT; int n = tt / WOUT;
    const int plane = WOUT * WOUT;
    int aoff = (n * WOUT + oy) * WOUT + ox;
    float a0 = alpha[aoff], a1 = alpha[8 * plane + aoff];
    float rho = sqrtf(a0 * a0 + a1 * a1);
    float inv = 1.0f / (rho + 1e-8f);
    float c1 = a0 * inv, s1 = a1 * inv;
    float c2 = c1 * c1 - s1 * s1, s2 = 2.0f * s1 * c1;
    float c3 = c2 * c1 - s2 * s1, s3 = s2 * c1 + c2 * s1;
    int py = oy & 1, px = ox & 1;
    int iy0 = (oy >> 1) + 1, ix0 = (ox >> 1) + 1;
    float eb[9][9]; int off[9];
    #pragma unroll
    for (int t = 0; t < 9; ++t) {
        int ty = t / 3, tx = t % 3;
        int ky = py + 2 * ty, kx = px + 2 * tx;
        int iy = iy0 - ty, ix = ix0 - tx;
        bool v = (ky < 5) && (kx < 5) && (iy >= 0) && (iy < HIN) && (ix >= 0) && (ix < HIN);
        float m = v ? 1.0f : 0.0f;
        int ciy = min(max(iy, 0), HIN - 1), cix = min(max(ix, 0), HIN - 1);
        off[t] = ciy * HIN + cix;
        int bi_ = min(ky, 4) * 5 + min(kx, 4);
        eb[0][t] = sb[0 * 25 + bi_] * m;
        eb[1][t] = sb[1 * 25 + bi_] * m;
        eb[2][t] = sb[2 * 25 + bi_] * m;
        eb[3][t] = (sb[3 * 25 + bi_] * c1 + sb[5 * 25 + bi_] * s1) * m;
        eb[4][t] = (sb[4 * 25 + bi_] * c1 + sb[6 * 25 + bi_] * s1) * m;
        eb[5][t] = (sb[7 * 25 + bi_] * c2 + sb[9 * 25 + bi_] * s2) * m;
        eb[6][t] = (sb[8 * 25 + bi_] * c2 + sb[10 * 25 + bi_] * s2) * m;
        eb[7][t] = (sb[11 * 25 + bi_] * c3 + sb[13 * 25 + bi_] * s3) * m;
        eb[8][t] = (sb[12 * 25 + bi_] * c3 + sb[14 * 25 + bi_] * s3) * m;
    }
    float acc[NOUT];
    #pragma unroll
    for (int o = 0; o < NOUT; ++o) acc[o] = 0.0f;
    const float* xn = x + (size_t)n * NIN * HIN * HIN;
    for (int i = 0; i < NIN; ++i) {
        const float* xp = xn + (size_t)i * HIN * HIN;
        float tap[9];
        #pragma unroll
        for (int t = 0; t < 9; ++t) tap[t] = xp[off[t]];
        float G[9];
        #pragma unroll
        for (int b = 0; b < 9; ++b) {
            float s = 0.0f;
            #pragma unroll
            for (int t = 0; t < 9; ++t) s += eb[b][t] * tap[t];
            G[b] = s;
        }
        const float* wp = weights + i * 9;
        #pragma unroll
        for (int o = 0; o < NOUT; ++o) {
            float s = acc[o];
            #pragma unroll
            for (int b = 0; b < 9; ++b) s += wp[o * NIN * 9 + b] * G[b];
            acc[o] = s;
        }
    }
    #pragma unroll
    for (int o = 0; o < NOUT; ++o)
        out[((size_t)(n * NOUT + o) * WOUT + oy) * WOUT + ox] = rho * acc[o] + bias[o];
}

extern "C" void kernel_launch(void* const* d_in, const int* in_sizes, int n_in,
                              void* d_out, int out_size, void* d_ws, size_t ws_size,
                              hipStream_t stream) {
    const float* x       = (const float*)d_in[0];
    const float* alpha   = (const float*)d_in[1];
    const float* weights = (const float*)d_in[2];
    const float* bias    = (const float*)d_in[3];
    float* out = (float*)d_out;

    const size_t hoff = 32768;
    const size_t perb = HQBATCH * 16;        // bytes per batch of h
    int cb = 0;
    if (ws_size > hoff) cb = (int)((ws_size - hoff) / perb);
    if (cb > 8) cb = 8;

    if (cb < 1) {
        const int pixels = 8 * WOUT * WOUT;
        steered_convT<<<dim3(pixels / 256), 256, 0, stream>>>(x, alpha, weights, bias, out);
        return;
    }

    float* Wt = (float*)d_ws;
    uint4* hq = (uint4*)((char*)d_ws + hoff);

    kprep_w<<<dim3(18), 256, 0, stream>>>(weights, Wt);

    for (int n0 = 0; n0 < 8; n0 += cb) {
        int nb = 8 - n0; if (nb > cb) nb = cb;
        kzero<<<dim3((nb * 772 + 255) / 256), 256, 0, stream>>>(hq, nb);
        kA<<<dim3(144, nb), 256, 0, stream>>>(x, Wt, hq, n0);
        kB<<<dim3(576 * nb), 512, 0, stream>>>(hq, alpha, bias, out, n0, nb);
    }
}

// Round 14
// 138.730 us; speedup vs baseline: 1.1706x; 1.0819x over previous
//
#include <hip/hip_runtime.h>

#define HIN 192
#define WOUT 384
#define NIN 32
#define NOUT 16
#define NSLOT 9
#define HP 194
#define HPLANE (HP * HP)                   // positions per plane (37636)
#define HQBATCH ((size_t)HPLANE * 18)      // uint4 elems per batch (18 quad-planes)

typedef float v2f __attribute__((ext_vector_type(2)));

__device__ __forceinline__ unsigned short f2bf(float f) {
    union { float f; unsigned int u; } v; v.f = f;
    unsigned int r = v.u + 0x7fffu + ((v.u >> 16) & 1u);   // RNE
    return (unsigned short)(r >> 16);
}
// lo: exact bf16 (shift). hi: RAW dword as f32 (bf16 + junk tail <= 2^-7 relative).
__device__ __forceinline__ v2f up2(unsigned u) {
    v2f r;
    r.x = __uint_as_float(u << 16);
    r.y = __uint_as_float(u);
    return r;
}

// ---- prep: Wt[c*256 + i*8 + j] = W[o][i][s],  m=c*8+j, s=m>>4, o=m&15 ----
__global__ __launch_bounds__(256) void kprep_w(const float* __restrict__ w, float* __restrict__ Wt) {
    int t = blockIdx.x * 256 + threadIdx.x;
    if (t >= NIN * NSLOT * NOUT) return;   // 4608
    int c = t >> 8, r = t & 255;
    int i = r >> 3, j = r & 7;
    int m = c * 8 + j;
    int s = m >> 4, o = m & 15;
    Wt[t] = w[(o * NIN + i) * NSLOT + s];
}

// ---- zero the 1-px halo border of every quad-plane ----
__global__ __launch_bounds__(256) void kzero(uint4* __restrict__ hq, int nb) {
    int t = blockIdx.x * 256 + threadIdx.x;
    if (t >= nb * 772) return;
    int b = t / 772, r = t % 772;
    int iy, ix;
    if (r < 194)      { iy = 0;           ix = r; }
    else if (r < 388) { iy = 193;         ix = r - 194; }
    else if (r < 580) { iy = r - 388 + 1; ix = 0; }
    else              { iy = r - 580 + 1; ix = 193; }
    uint4* p = hq + (size_t)b * HQBATCH + iy * HP + ix;
    uint4 z; z.x = 0; z.y = 0; z.z = 0; z.w = 0;
    #pragma unroll
    for (int c = 0; c < 18; ++c) p[(size_t)c * HPLANE] = z;
}

// ---- kA: channel mix at input resolution -> quad-plane bf16 pairs ----
__global__ __launch_bounds__(256) void kA(const float* __restrict__ x,
                                          const float* __restrict__ Wt,
                                          uint4* __restrict__ hq, int n0) {
    const int b = blockIdx.y;
    const int n = n0 + b;
    const int px = blockIdx.x * 256 + threadIdx.x;   // 0..36863
    const int iy = px / HIN, ix = px % HIN;
    const float* xp = x + (size_t)n * NIN * HIN * HIN + px;
    float xv[NIN];
    #pragma unroll
    for (int i = 0; i < NIN; ++i) xv[i] = xp[(size_t)i * HIN * HIN];
    const int pos = (iy + 1) * HP + (ix + 1);
    uint4* hb = hq + (size_t)b * HQBATCH;
    #pragma unroll 1
    for (int c = 0; c < 18; ++c) {
        const float* wc = Wt + c * 256;              // uniform -> scalar loads
        float a[8];
        #pragma unroll
        for (int j = 0; j < 8; ++j) a[j] = 0.0f;
        #pragma unroll
        for (int i = 0; i < NIN; ++i) {
            const float xi = xv[i];
            #pragma unroll
            for (int j = 0; j < 8; ++j) a[j] = fmaf(wc[i * 8 + j], xi, a[j]);
        }
        uint4 v;
        v.x = (unsigned)f2bf(a[0]) | ((unsigned)f2bf(a[1]) << 16);
        v.y = (unsigned)f2bf(a[2]) | ((unsigned)f2bf(a[3]) << 16);
        v.z = (unsigned)f2bf(a[4]) | ((unsigned)f2bf(a[5]) << 16);
        v.w = (unsigned)f2bf(a[6]) | ((unsigned)f2bf(a[7]) << 16);
        hb[(size_t)c * HPLANE + pos] = v;
    }
}

// ---- angle state from alpha for one output pixel ----
__device__ __forceinline__ void angles(const float* __restrict__ alpha, int n, int oy, int ox,
                                       float (&cc)[3], float (&ss)[3], float& rr) {
    const int aoff = (n * WOUT + oy) * WOUT + ox;
    const float a0 = alpha[aoff];
    const float a1 = alpha[(size_t)8 * WOUT * WOUT + aoff];
    rr = sqrtf(a0 * a0 + a1 * a1);
    const float inv = 1.0f / (rr + 1e-8f);
    cc[0] = a0 * inv;                      ss[0] = a1 * inv;
    cc[1] = cc[0] * cc[0] - ss[0] * ss[0]; ss[1] = 2.0f * cc[0] * ss[0];
    cc[2] = cc[1] * cc[0] - ss[1] * ss[0]; ss[2] = ss[1] * cc[0] + cc[1] * ss[0];
}

__device__ __forceinline__ float ebv(const float2 C, int s,
                                     const float (&cc)[3], const float (&ss)[3]) {
    // s is a compile-time constant at each unrolled call site
    if (s < 3) return C.x;
    if (s < 5) return C.x * cc[0] + C.y * ss[0];
    if (s < 7) return C.x * cc[1] + C.y * ss[1];
    return C.x * cc[2] + C.y * ss[2];
}

// ---- kB body: one wave = (pair, half); one thread = one site, 2 parity pixels, 8 ch ----
// PAIR 0: A=(0,0) all 9 taps, B=(1,1) taps ty<2&&tx<2.
// PAIR 1: A=(0,1) taps tx<2,   B=(1,0) taps ty<2.
template<int PAIR, int HF>
__device__ __forceinline__ void kb_pair(const uint4* __restrict__ hb,
                                        const float* __restrict__ alpha,
                                        const float* __restrict__ bias_,
                                        float (&stage)[2][16][128],
                                        const float2 (&Cb)[NSLOT][25],
                                        int n, int Y, int X, int lane) {
    constexpr int AX = (PAIR == 0) ? 0 : 1;   // A = (PY=0, AX)
    constexpr int BX = (PAIR == 0) ? 1 : 0;   // B = (PY=1, BX)

    float ccA[3], ssA[3], ccB[3], ssB[3], rrA, rrB;
    angles(alpha, n, 2 * Y + 0, 2 * X + AX, ccA, ssA, rrA);
    angles(alpha, n, 2 * Y + 1, 2 * X + BX, ccB, ssB, rrB);

    v2f aA[4], aB[4];
    #pragma unroll
    for (int j = 0; j < 4; ++j) { aA[j].x = 0.0f; aA[j].y = 0.0f; aB[j].x = 0.0f; aB[j].y = 0.0f; }

    #pragma unroll 1
    for (int ty = 0; ty < 3; ++ty) {
        const int piy = Y + 2 - ty;
        #pragma unroll 1
        for (int tx = 0; tx < 3; ++tx) {
            const bool useA = (tx < 3 - AX);                 // A: PY=0 -> ty always valid
            const bool useB = (ty < 2) && (tx < 3 - BX);
            if (!useA && !useB) continue;                    // pair1 (2,2) only
            const int pix = X + 2 - tx;
            const unsigned pos = (unsigned)(piy * HP + pix);
            const int biA = (0 + 2 * ty) * 5 + (AX + 2 * tx);
            const int biB = (1 + 2 * ty) * 5 + (BX + 2 * tx);
            if (useA && useB) {
                #pragma unroll
                for (int s = 0; s < NSLOT; ++s) {
                    const uint4 v = hb[(size_t)(2 * s + HF) * HPLANE + pos];
                    const float eA = ebv(Cb[s][biA], s, ccA, ssA);
                    const float eB = ebv(Cb[s][biB], s, ccB, ssB);
                    v2f eA2; eA2.x = eA; eA2.y = eA;
                    v2f eB2; eB2.x = eB; eB2.y = eB;
                    v2f h0 = up2(v.x), h1 = up2(v.y), h2 = up2(v.z), h3 = up2(v.w);
                    aA[0] += eA2 * h0; aA[1] += eA2 * h1; aA[2] += eA2 * h2; aA[3] += eA2 * h3;
                    aB[0] += eB2 * h0; aB[1] += eB2 * h1; aB[2] += eB2 * h2; aB[3] += eB2 * h3;
                }
            } else if (useA) {
                #pragma unroll
                for (int s = 0; s < NSLOT; ++s) {
                    const uint4 v = hb[(size_t)(2 * s + HF) * HPLANE + pos];
                    const float eA = ebv(Cb[s][biA], s, ccA, ssA);
                    v2f eA2; eA2.x = eA; eA2.y = eA;
                    aA[0] += eA2 * up2(v.x); aA[1] += eA2 * up2(v.y);
                    aA[2] += eA2 * up2(v.z); aA[3] += eA2 * up2(v.w);
                }
            } else {
                #pragma unroll
                for (int s = 0; s < NSLOT; ++s) {
                    const uint4 v = hb[(size_t)(2 * s + HF) * HPLANE + pos];
                    const float eB = ebv(Cb[s][biB], s, ccB, ssB);
                    v2f eB2; eB2.x = eB; eB2.y = eB;
                    aB[0] += eB2 * up2(v.x); aB[1] += eB2 * up2(v.y);
                    aB[2] += eB2 * up2(v.z); aB[3] += eB2 * up2(v.w);
                }
            }
        }
    }

    #pragma unroll
    for (int j = 0; j < 4; ++j) {
        stage[0][HF * 8 + 2 * j + 0][2 * lane + AX] = rrA * aA[j].x + bias_[HF * 8 + 2 * j + 0];
        stage[0][HF * 8 + 2 * j + 1][2 * lane + AX] = rrA * aA[j].y + bias_[HF * 8 + 2 * j + 1];
        stage[1][HF * 8 + 2 * j + 0][2 * lane + BX] = rrB * aB[j].x + bias_[HF * 8 + 2 * j + 0];
        stage[1][HF * 8 + 2 * j + 1][2 * lane + BX] = rrB * aB[j].y + bias_[HF * 8 + 2 * j + 1];
    }
}

__global__ __launch_bounds__(256, 4) void kB(const uint4* __restrict__ hq,
                                             const float* __restrict__ alpha,
                                             const float* __restrict__ bias,
                                             float* __restrict__ out, int n0, int nb) {
    __shared__ float2 Cb[NSLOT][25];
    __shared__ float stage[2][16][128];
    {
        const int q = threadIdx.x;
        if (q < NSLOT * 25) {
            int s = q / 25, p = q % 25;
            int ky = p / 5, kx = p % 5;
            float ys = (float)(ky - 2), xs = (float)(kx - 2);
            float r = sqrtf(xs * xs + ys * ys);
            float th = atan2f(ys, xs);
            float cr, ci;
            if (s < 3) {
                float d = r - (float)s;
                cr = expf(-d * d * (1.0f / 0.72f));
                ci = 0.0f;
            } else {
                int k = (s - 3) / 2 + 1;
                float r0 = ((s - 3) & 1) ? 2.0f : 1.0f;
                float d = r - r0;
                float ring = expf(-d * d * (1.0f / 0.72f));
                float a = (float)k * th;
                cr = ring * cosf(a);
                ci = ring * sinf(a);
            }
            Cb[s][p] = make_float2(cr, ci);
        }
    }
    __syncthreads();

    // ---- bijective XCD swizzle, Y-fastest ----
    const int tot = gridDim.x;
    const int cpx = tot >> 3;
    const int swz = ((int)blockIdx.x & 7) * cpx + ((int)blockIdx.x >> 3);
    const int Y = swz % 192;
    const int rest = swz / 192;
    const int b = rest % nb;
    const int bx = rest / nb;

    const int n = n0 + b;
    const int lane = threadIdx.x & 63;
    const int wv = threadIdx.x >> 6;        // 0..3 = (HF, pair)
    const int X0 = bx * 64;
    const int X = X0 + lane;
    const uint4* hb = hq + (size_t)b * HQBATCH;

    switch (wv) {
        case 0: kb_pair<0, 0>(hb, alpha, bias, stage, Cb, n, Y, X, lane); break;
        case 1: kb_pair<1, 0>(hb, alpha, bias, stage, Cb, n, Y, X, lane); break;
        case 2: kb_pair<0, 1>(hb, alpha, bias, stage, Cb, n, Y, X, lane); break;
        default: kb_pair<1, 1>(hb, alpha, bias, stage, Cb, n, Y, X, lane); break;
    }

    __syncthreads();

    // cooperative coalesced store: 2 oy-rows x 16 channels x 128 px (4096 floats)
    #pragma unroll
    for (int q = 0; q < 16; ++q) {
        const int f = q * 256 + threadIdx.x;
        const int row = f >> 7, col = f & 127;
        const int py = row >> 4, o = row & 15;
        out[(((size_t)n * NOUT + o) * WOUT + (2 * Y + py)) * WOUT + 2 * X0 + col]
            = stage[py][o][col];
    }
}

// ---- fallback: proven round-1 monolithic kernel ----
__global__ __launch_bounds__(256) void steered_convT(
    const float* __restrict__ x, const float* __restrict__ alpha,
    const float* __restrict__ weights, const float* __restrict__ bias,
    float* __restrict__ out) {
    __shared__ float sb[15 * 25];
    for (int q = threadIdx.x; q < 375; q += 256) {
        int s = q / 25, p = q % 25;
        int ky = p / 5, kx = p % 5;
        float ys = (float)(ky - 2), xs = (float)(kx - 2);
        float r = sqrtf(xs * xs + ys * ys);
        float th = atan2f(ys, xs);
        float val;
        if (s < 3) { float d = r - (float)s; val = expf(-d * d * (1.0f / 0.72f)); }
        else {
            int k = (s - 3) / 4 + 1; int rem = (s - 3) & 3;
            float r0 = (rem & 1) ? 2.0f : 1.0f; float d = r - r0;
            float ring = expf(-d * d * (1.0f / 0.72f));
            float ang = (float)k * th;
            val = ring * ((rem < 2) ? cosf(ang) : sinf(ang));
        }
        sb[q] = val;
    }
    __syncthreads();
    int idx = blockIdx.x * 256 + threadIdx.x;
    int ox = idx % WOUT; int tt = idx / WOUT; int oy = tt % WOUT; int n = tt / WOUT;
    const int plane = WOUT * WOUT;
    int aoff = (n * WOUT + oy) * WOUT + ox;
    float a0 = alpha[aoff], a1 = alpha[8 * plane + aoff];
    float rho = sqrtf(a0 * a0 + a1 * a1);
    float inv = 1.0f / (rho + 1e-8f);
    float c1 = a0 * inv, s1 = a1 * inv;
    float c2 = c1 * c1 - s1 * s1, s2 = 2.0f * s1 * c1;
    float c3 = c2 * c1 - s2 * s1, s3 = s2 * c1 + c2 * s1;
    int py = oy & 1, px = ox & 1;
    int iy0 = (oy >> 1) + 1, ix0 = (ox >> 1) + 1;
    float eb[9][9]; int off[9];
    #pragma unroll
    for (int t = 0; t < 9; ++t) {
        int ty = t / 3, tx = t % 3;
        int ky = py + 2 * ty, kx = px + 2 * tx;
        int iy = iy0 - ty, ix = ix0 - tx;
        bool v = (ky < 5) && (kx < 5) && (iy >= 0) && (iy < HIN) && (ix >= 0) && (ix < HIN);
        float m = v ? 1.0f : 0.0f;
        int ciy = min(max(iy, 0), HIN - 1), cix = min(max(ix, 0), HIN - 1);
        off[t] = ciy * HIN + cix;
        int bi_ = min(ky, 4) * 5 + min(kx, 4);
        eb[0][t] = sb[0 * 25 + bi_] * m;
        eb[1][t] = sb[1 * 25 + bi_] * m;
        eb[2][t] = sb[2 * 25 + bi_] * m;
        eb[3][t] = (sb[3 * 25 + bi_] * c1 + sb[5 * 25 + bi_] * s1) * m;
        eb[4][t] = (sb[4 * 25 + bi_] * c1 + sb[6 * 25 + bi_] * s1) * m;
        eb[5][t] = (sb[7 * 25 + bi_] * c2 + sb[9 * 25 + bi_] * s2) * m;
        eb[6][t] = (sb[8 * 25 + bi_] * c2 + sb[10 * 25 + bi_] * s2) * m;
        eb[7][t] = (sb[11 * 25 + bi_] * c3 + sb[13 * 25 + bi_] * s3) * m;
        eb[8][t] = (sb[12 * 25 + bi_] * c3 + sb[14 * 25 + bi_] * s3) * m;
    }
    float acc[NOUT];
    #pragma unroll
    for (int o = 0; o < NOUT; ++o) acc[o] = 0.0f;
    const float* xn = x + (size_t)n * NIN * HIN * HIN;
    for (int i = 0; i < NIN; ++i) {
        const float* xp = xn + (size_t)i * HIN * HIN;
        float tap[9];
        #pragma unroll
        for (int t = 0; t < 9; ++t) tap[t] = xp[off[t]];
        float G[9];
        #pragma unroll
        for (int b = 0; b < 9; ++b) {
            float s = 0.0f;
            #pragma unroll
            for (int t = 0; t < 9; ++t) s += eb[b][t] * tap[t];
            G[b] = s;
        }
        const float* wp = weights + i * 9;
        #pragma unroll
        for (int o = 0; o < NOUT; ++o) {
            float s = acc[o];
            #pragma unroll
            for (int b = 0; b < 9; ++b) s += wp[o * NIN * 9 + b] * G[b];
            acc[o] = s;
        }
    }
    #pragma unroll
    for (int o = 0; o < NOUT; ++o)
        out[((size_t)(n * NOUT + o) * WOUT + oy) * WOUT + ox] = rho * acc[o] + bias[o];
}

extern "C" void kernel_launch(void* const* d_in, const int* in_sizes, int n_in,
                              void* d_out, int out_size, void* d_ws, size_t ws_size,
                              hipStream_t stream) {
    const float* x       = (const float*)d_in[0];
    const float* alpha   = (const float*)d_in[1];
    const float* weights = (const float*)d_in[2];
    const float* bias    = (const float*)d_in[3];
    float* out = (float*)d_out;

    const size_t hoff = 32768;
    const size_t perb = HQBATCH * 16;        // bytes per batch of h
    int cb = 0;
    if (ws_size > hoff) cb = (int)((ws_size - hoff) / perb);
    if (cb > 8) cb = 8;

    if (cb < 1) {
        const int pixels = 8 * WOUT * WOUT;
        steered_convT<<<dim3(pixels / 256), 256, 0, stream>>>(x, alpha, weights, bias, out);
        return;
    }

    float* Wt = (float*)d_ws;
    uint4* hq = (uint4*)((char*)d_ws + hoff);

    kprep_w<<<dim3(18), 256, 0, stream>>>(weights, Wt);

    for (int n0 = 0; n0 < 8; n0 += cb) {
        int nb = 8 - n0; if (nb > cb) nb = cb;
        kzero<<<dim3((nb * 772 + 255) / 256), 256, 0, stream>>>(hq, nb);
        kA<<<dim3(144, nb), 256, 0, stream>>>(x, Wt, hq, n0);
        kB<<<dim3(576 * nb), 256, 0, stream>>>(hq, alpha, bias, out, n0, nb);
    }
}